// Round 14
// baseline (356.492 us; speedup 1.0000x reference)
//
#include <hip/hip_runtime.h>
#include <math.h>

#define NN_F 50000      // nodes per frame
#define NE_F 400000     // edges per frame
#define BPF  768        // blocks per frame for fused agg2+mean (32 groups/block)

__device__ __forceinline__ float lrelu02(float x) { return x > 0.f ? x : 0.2f * x; }
__device__ __forceinline__ float fexp(float x) { return __expf(x); }

// bf16 pack (RNE) / unpack helpers
__device__ __forceinline__ unsigned short f2bf(float f) {
  unsigned int u = __float_as_uint(f);
  u += 0x7fffu + ((u >> 16) & 1u);
  return (unsigned short)(u >> 16);
}
__device__ __forceinline__ float bf_lo(unsigned int u) { return __uint_as_float(u << 16); }
__device__ __forceinline__ float bf_hi(unsigned int u) { return __uint_as_float(u & 0xffff0000u); }
__device__ __forceinline__ unsigned int pack2(float a, float b) {
  return (unsigned int)f2bf(a) | ((unsigned int)f2bf(b) << 16);
}

typedef __attribute__((ext_vector_type(8))) short bfrag_t;   // 8 bf16 (4 VGPRs)
typedef __attribute__((ext_vector_type(4))) float facc_t;    // 4 fp32 acc

// ---- FUSED: CSR rank pass (atomic-bound) ∥ GAT1 node linear (VALU/LDS-bound) ----
// node1's weights live in LDS (not registers) so the shared 24-VGPR allocation
// cannot trigger global-load rematerialization (round-12/13 pathology).
__global__ void __launch_bounds__(256, 3)
k_rank_node1(const int* __restrict__ ei, int* __restrict__ deg,
             unsigned short* __restrict__ rank, int nFrames, int rankBlocks,
             const float* __restrict__ x, const float* __restrict__ W1,
             const float* __restrict__ attS, const float* __restrict__ attD,
             unsigned short* __restrict__ h1b, float* __restrict__ as1,
             float* __restrict__ ad1, int nNodes, int node1Blocks) {
  __shared__ float sW1[64][17];    // stride 17: lane l -> 2 lanes/bank (conflict-free)
  __shared__ float sAtt[2][64];
  __shared__ float xbuf[4][16];
  if (blockIdx.x < rankBlocks) {
    // ---- rank role ----
    int tid = blockIdx.x * blockDim.x + threadIdx.x;
    int T = (nFrames * NE_F) >> 2;
    if (tid >= T) return;
    int gd[4];
#pragma unroll
    for (int i = 0; i < 4; i++) {
      int e = tid + i * T;
      int f = e / NE_F, idx = e - f * NE_F;
      gd[i] = f * NN_F + ei[(size_t)f * 2 * NE_F + NE_F + idx];
    }
    int r[4];
#pragma unroll
    for (int i = 0; i < 4; i++) r[i] = atomicAdd(&deg[gd[i]], 1);
#pragma unroll
    for (int i = 0; i < 4; i++) rank[tid + i * T] = (unsigned short)r[i];
    return;
  }
  // ---- node1 role ----
  for (int i = threadIdx.x; i < 64 * 13; i += 256) sW1[i / 13][i % 13] = W1[i];
  if (threadIdx.x < 64) {
    sAtt[0][threadIdx.x] = attS[threadIdx.x];
    sAtt[1][threadIdx.x] = attD[threadIdx.x];
  }
  __syncthreads();
  int bid = blockIdx.x - rankBlocks;
  int l = threadIdx.x & 63;
  int w = threadIdx.x >> 6;
  int wid = (bid * blockDim.x + threadIdx.x) >> 6;
  int nw = (node1Blocks * blockDim.x) >> 6;
  for (int n = wid; n < nNodes; n += nw) {
    if (l < 16) xbuf[w][l] = (l < 13) ? x[(size_t)n * 13 + l] : 0.f;
    float a0 = 0.f, a1 = 0.f, a2 = 0.f, a3 = 0.f;
#pragma unroll
    for (int c = 0; c < 12; c += 4) {
      a0 = fmaf(xbuf[w][c + 0], sW1[l][c + 0], a0);
      a1 = fmaf(xbuf[w][c + 1], sW1[l][c + 1], a1);
      a2 = fmaf(xbuf[w][c + 2], sW1[l][c + 2], a2);
      a3 = fmaf(xbuf[w][c + 3], sW1[l][c + 3], a3);
    }
    a0 = fmaf(xbuf[w][12], sW1[l][12], a0);
    float acc = (a0 + a1) + (a2 + a3);
    h1b[(size_t)n * 64 + l] = f2bf(acc);
    float s = acc * sAtt[0][l], d = acc * sAtt[1][l];
#pragma unroll
    for (int off = 1; off < 8; off <<= 1) {
      s += __shfl_xor(s, off, 64);
      d += __shfl_xor(d, off, 64);
    }
    if ((l & 7) == 0) { as1[n * 8 + (l >> 3)] = s; ad1[n * 8 + (l >> 3)] = d; }
  }
}

// ---------------- CSR build: per-block sums ----------------
__global__ void k_scan1(const int* __restrict__ deg, int* __restrict__ bsum, int nNodes) {
  __shared__ int part[256];
  int t = threadIdx.x;
  int i = blockIdx.x * 256 + t;
  part[t] = (i < nNodes) ? deg[i] : 0;
  __syncthreads();
  for (int off = 128; off > 0; off >>= 1) {
    if (t < off) part[t] += part[t + off];
    __syncthreads();
  }
  if (t == 0) bsum[blockIdx.x] = part[0];
}

// ---------------- CSR build: scan of block sums (single block, up to 1024) ----------------
__global__ void __launch_bounds__(1024)
k_scan2(const int* __restrict__ bsum, int* __restrict__ boff, int nblk) {
  __shared__ int part[1024];
  int t = threadIdx.x;
  part[t] = (t < nblk) ? bsum[t] : 0;
  __syncthreads();
  for (int off = 1; off < 1024; off <<= 1) {
    int v = (t >= off) ? part[t - off] : 0;
    __syncthreads();
    part[t] += v;
    __syncthreads();
  }
  if (t < nblk) boff[t] = part[t] - bsum[t];  // exclusive
}

// ---------------- CSR build: intra-block scan -> rowptr ----------------
__global__ void k_scan3(const int* __restrict__ deg, const int* __restrict__ boff,
                        int* __restrict__ rowptr, int nNodes, int nEdges) {
  __shared__ int part[256];
  int t = threadIdx.x;
  int i = blockIdx.x * 256 + t;
  int d = (i < nNodes) ? deg[i] : 0;
  part[t] = d;
  __syncthreads();
  for (int off = 1; off < 256; off <<= 1) {
    int v = (t >= off) ? part[t - off] : 0;
    __syncthreads();
    part[t] += v;
    __syncthreads();
  }
  if (i < nNodes) rowptr[i] = boff[blockIdx.x] + part[t] - d;  // exclusive prefix
  if (blockIdx.x == 0 && t == 0) rowptr[nNodes] = nEdges;
}

// ---- CSR build pass B: place srcs (NO atomics; 4x ILP) ----
__global__ void k_place(const int* __restrict__ ei, const int* __restrict__ rowptr,
                        const unsigned short* __restrict__ rank, int* __restrict__ csr,
                        int nFrames) {
  int tid = blockIdx.x * blockDim.x + threadIdx.x;
  int T = (nFrames * NE_F) >> 2;
  if (tid >= T) return;
#pragma unroll
  for (int i = 0; i < 4; i++) {
    int e = tid + i * T;
    int f = e / NE_F, idx = e - f * NE_F;
    const int* base = ei + (size_t)f * 2 * NE_F;
    int src = base[idx], dst = base[NE_F + idx];
    csr[rowptr[f * NN_F + dst] + (int)rank[e]] = f * NN_F + src;
  }
}

// single-edge accumulate helper (bf16 gather)
#define EDGE_ACC(tab, srcv, attarr, attidx)                          \
  {                                                                  \
    float e2 = fexp(lrelu02(attarr[attidx] + adv));                  \
    uint4 v = *reinterpret_cast<const uint4*>(tab + (size_t)(srcv) * 64 + q * 8); \
    a0 = fmaf(e2, bf_lo(v.x), a0); a1 = fmaf(e2, bf_hi(v.x), a1);    \
    a2 = fmaf(e2, bf_lo(v.y), a2); a3 = fmaf(e2, bf_hi(v.y), a3);    \
    a4 = fmaf(e2, bf_lo(v.z), a4); a5 = fmaf(e2, bf_hi(v.z), a5);    \
    a6 = fmaf(e2, bf_lo(v.w), a6); a7 = fmaf(e2, bf_hi(v.w), a7);    \
    den += e2;                                                       \
  }

// ---- GAT layer 1 aggregation: GROUP(8 lanes)-PER-NODE; lane q = head q ----
__global__ void __launch_bounds__(256)
k_agg1(const int* __restrict__ rowptr, const int* __restrict__ csr,
       const unsigned short* __restrict__ h1b, const float* __restrict__ as1,
       const float* __restrict__ ad1, unsigned short* __restrict__ out1b, int nNodes) {
  int t = threadIdx.x;
  int l = t & 63;
  int grp = l >> 3, q = l & 7;
  int n = ((blockIdx.x * blockDim.x + t) >> 6) * 8 + grp;   // group -> node
  if (n >= nNodes) return;
  float adv = ad1[n * 8 + q];
  float e0 = fexp(lrelu02(as1[n * 8 + q] + adv));
  uint4 pv = *reinterpret_cast<const uint4*>(h1b + (size_t)n * 64 + q * 8);
  float a0 = e0 * bf_lo(pv.x), a1 = e0 * bf_hi(pv.x);
  float a2 = e0 * bf_lo(pv.y), a3 = e0 * bf_hi(pv.y);
  float a4 = e0 * bf_lo(pv.z), a5 = e0 * bf_hi(pv.z);
  float a6 = e0 * bf_lo(pv.w), a7 = e0 * bf_hi(pv.w);
  float den = e0;
  int s0 = rowptr[n], s1 = rowptr[n + 1];
  int i = s0;
  for (; i + 4 <= s1; i += 4) {   // 4-way unroll: 4 gather chains in flight per group
    int sa = csr[i], sb = csr[i + 1], sc = csr[i + 2], sd = csr[i + 3];
    float ea = fexp(lrelu02(as1[sa * 8 + q] + adv));
    float eb = fexp(lrelu02(as1[sb * 8 + q] + adv));
    float ec = fexp(lrelu02(as1[sc * 8 + q] + adv));
    float ed = fexp(lrelu02(as1[sd * 8 + q] + adv));
    uint4 va = *reinterpret_cast<const uint4*>(h1b + (size_t)sa * 64 + q * 8);
    uint4 vb = *reinterpret_cast<const uint4*>(h1b + (size_t)sb * 64 + q * 8);
    uint4 vc = *reinterpret_cast<const uint4*>(h1b + (size_t)sc * 64 + q * 8);
    uint4 vd = *reinterpret_cast<const uint4*>(h1b + (size_t)sd * 64 + q * 8);
    a0 = fmaf(ea, bf_lo(va.x), a0); a1 = fmaf(ea, bf_hi(va.x), a1);
    a2 = fmaf(ea, bf_lo(va.y), a2); a3 = fmaf(ea, bf_hi(va.y), a3);
    a4 = fmaf(ea, bf_lo(va.z), a4); a5 = fmaf(ea, bf_hi(va.z), a5);
    a6 = fmaf(ea, bf_lo(va.w), a6); a7 = fmaf(ea, bf_hi(va.w), a7);
    a0 = fmaf(eb, bf_lo(vb.x), a0); a1 = fmaf(eb, bf_hi(vb.x), a1);
    a2 = fmaf(eb, bf_lo(vb.y), a2); a3 = fmaf(eb, bf_hi(vb.y), a3);
    a4 = fmaf(eb, bf_lo(vb.z), a4); a5 = fmaf(eb, bf_hi(vb.z), a5);
    a6 = fmaf(eb, bf_lo(vb.w), a6); a7 = fmaf(eb, bf_hi(vb.w), a7);
    a0 = fmaf(ec, bf_lo(vc.x), a0); a1 = fmaf(ec, bf_hi(vc.x), a1);
    a2 = fmaf(ec, bf_lo(vc.y), a2); a3 = fmaf(ec, bf_hi(vc.y), a3);
    a4 = fmaf(ec, bf_lo(vc.z), a4); a5 = fmaf(ec, bf_hi(vc.z), a5);
    a6 = fmaf(ec, bf_lo(vc.w), a6); a7 = fmaf(ec, bf_hi(vc.w), a7);
    a0 = fmaf(ed, bf_lo(vd.x), a0); a1 = fmaf(ed, bf_hi(vd.x), a1);
    a2 = fmaf(ed, bf_lo(vd.y), a2); a3 = fmaf(ed, bf_hi(vd.y), a3);
    a4 = fmaf(ed, bf_lo(vd.z), a4); a5 = fmaf(ed, bf_hi(vd.z), a5);
    a6 = fmaf(ed, bf_lo(vd.w), a6); a7 = fmaf(ed, bf_hi(vd.w), a7);
    den += (ea + eb) + (ec + ed);
  }
  for (; i < s1; i++) {
    int src = csr[i];
    EDGE_ACC(h1b, src, as1, src * 8 + q)
  }
  float inv = 1.f / den;
  uint4 o;
  o.x = pack2(a0 * inv, a1 * inv);
  o.y = pack2(a2 * inv, a3 * inv);
  o.z = pack2(a4 * inv, a5 * inv);
  o.w = pack2(a6 * inv, a7 * inv);
  *reinterpret_cast<uint4*>(out1b + (size_t)n * 64 + q * 8) = o;
}

// ---------------- node2 via MFMA: wave = 16-node tile ----------------
__global__ void __launch_bounds__(256)
k_node2(const unsigned short* __restrict__ out1b, const float* __restrict__ b1,
        const float* __restrict__ W2, const float* __restrict__ attS2,
        const float* __restrict__ attD2, unsigned short* __restrict__ gb,
        float* __restrict__ as2, float* __restrict__ ad2, int nNodes) {
  __shared__ unsigned short lg[4][16][72];   // per-wave 16x64 bf16, row stride 72 (16B-aligned)
  int t = threadIdx.x, l = t & 63, w = t >> 6;
  int r16 = l & 15, g4 = l >> 4;

  bfrag_t bfr[8];
#pragma unroll
  for (int tt = 0; tt < 4; tt++) {
    const float* wrow = W2 + (tt * 16 + r16) * 64;
#pragma unroll
    for (int kc = 0; kc < 2; kc++) {
      float4 lo = *reinterpret_cast<const float4*>(wrow + kc * 32 + 4 * g4);
      float4 hi = *reinterpret_cast<const float4*>(wrow + kc * 32 + 16 + 4 * g4);
      union { unsigned short u[8]; bfrag_t v; } pk;
      pk.u[0] = f2bf(lo.x); pk.u[1] = f2bf(lo.y); pk.u[2] = f2bf(lo.z); pk.u[3] = f2bf(lo.w);
      pk.u[4] = f2bf(hi.x); pk.u[5] = f2bf(hi.y); pk.u[6] = f2bf(hi.z); pk.u[7] = f2bf(hi.w);
      bfr[tt * 2 + kc] = pk.v;
    }
  }
  float4 bias[2][2];
#pragma unroll
  for (int kc = 0; kc < 2; kc++)
#pragma unroll
    for (int h = 0; h < 2; h++)
      bias[kc][h] = *reinterpret_cast<const float4*>(b1 + kc * 32 + h * 16 + 4 * g4);
  float aSr0 = attS2[r16], aSr1 = attS2[16 + r16], aSr2 = attS2[32 + r16], aSr3 = attS2[48 + r16];
  float aDr0 = attD2[r16], aDr1 = attD2[16 + r16], aDr2 = attD2[32 + r16], aDr3 = attD2[48 + r16];

  int wid = (blockIdx.x * blockDim.x + t) >> 6;
  int nw = (gridDim.x * blockDim.x) >> 6;
  int ntiles = nNodes >> 4;
  for (int tile = wid; tile < ntiles; tile += nw) {
    int n0 = tile << 4;
    const unsigned short* arow = out1b + (size_t)(n0 + r16) * 64;
    facc_t acc0 = 0, acc1 = 0, acc2 = 0, acc3 = 0;
#pragma unroll
    for (int kc = 0; kc < 2; kc++) {
      union { unsigned short u[8]; bfrag_t v; } apk;
#pragma unroll
      for (int h = 0; h < 2; h++) {
        uint2 raw = *reinterpret_cast<const uint2*>(arow + kc * 32 + h * 16 + 4 * g4);
        float4 bb = bias[kc][h];
        float f0 = bf_lo(raw.x) + bb.x, f1 = bf_hi(raw.x) + bb.y;
        float f2 = bf_lo(raw.y) + bb.z, f3 = bf_hi(raw.y) + bb.w;
        f0 = f0 > 0.f ? f0 : (fexp(f0) - 1.f);
        f1 = f1 > 0.f ? f1 : (fexp(f1) - 1.f);
        f2 = f2 > 0.f ? f2 : (fexp(f2) - 1.f);
        f3 = f3 > 0.f ? f3 : (fexp(f3) - 1.f);
        apk.u[h * 4 + 0] = f2bf(f0); apk.u[h * 4 + 1] = f2bf(f1);
        apk.u[h * 4 + 2] = f2bf(f2); apk.u[h * 4 + 3] = f2bf(f3);
      }
      bfrag_t afr = apk.v;
      acc0 = __builtin_amdgcn_mfma_f32_16x16x32_bf16(afr, bfr[0 * 2 + kc], acc0, 0, 0, 0);
      acc1 = __builtin_amdgcn_mfma_f32_16x16x32_bf16(afr, bfr[1 * 2 + kc], acc1, 0, 0, 0);
      acc2 = __builtin_amdgcn_mfma_f32_16x16x32_bf16(afr, bfr[2 * 2 + kc], acc2, 0, 0, 0);
      acc3 = __builtin_amdgcn_mfma_f32_16x16x32_bf16(afr, bfr[3 * 2 + kc], acc3, 0, 0, 0);
    }
    float ps0 = acc0[0] * aSr0 + acc1[0] * aSr1 + acc2[0] * aSr2 + acc3[0] * aSr3;
    float ps1 = acc0[1] * aSr0 + acc1[1] * aSr1 + acc2[1] * aSr2 + acc3[1] * aSr3;
    float ps2 = acc0[2] * aSr0 + acc1[2] * aSr1 + acc2[2] * aSr2 + acc3[2] * aSr3;
    float ps3 = acc0[3] * aSr0 + acc1[3] * aSr1 + acc2[3] * aSr2 + acc3[3] * aSr3;
    float pd0 = acc0[0] * aDr0 + acc1[0] * aDr1 + acc2[0] * aDr2 + acc3[0] * aDr3;
    float pd1 = acc0[1] * aDr0 + acc1[1] * aDr1 + acc2[1] * aDr2 + acc3[1] * aDr3;
    float pd2 = acc0[2] * aDr0 + acc1[2] * aDr1 + acc2[2] * aDr2 + acc3[2] * aDr3;
    float pd3 = acc0[3] * aDr0 + acc1[3] * aDr1 + acc2[3] * aDr2 + acc3[3] * aDr3;
#pragma unroll
    for (int off = 1; off < 16; off <<= 1) {
      ps0 += __shfl_xor(ps0, off, 64); ps1 += __shfl_xor(ps1, off, 64);
      ps2 += __shfl_xor(ps2, off, 64); ps3 += __shfl_xor(ps3, off, 64);
      pd0 += __shfl_xor(pd0, off, 64); pd1 += __shfl_xor(pd1, off, 64);
      pd2 += __shfl_xor(pd2, off, 64); pd3 += __shfl_xor(pd3, off, 64);
    }
    if (r16 == 0) {
      *reinterpret_cast<float4*>(as2 + n0 + g4 * 4) = make_float4(ps0, ps1, ps2, ps3);
      *reinterpret_cast<float4*>(ad2 + n0 + g4 * 4) = make_float4(pd0, pd1, pd2, pd3);
    }
#pragma unroll
    for (int r = 0; r < 4; r++) {
      lg[w][g4 * 4 + r][0 * 16 + r16] = f2bf(acc0[r]);
      lg[w][g4 * 4 + r][1 * 16 + r16] = f2bf(acc1[r]);
      lg[w][g4 * 4 + r][2 * 16 + r16] = f2bf(acc2[r]);
      lg[w][g4 * 4 + r][3 * 16 + r16] = f2bf(acc3[r]);
    }
    asm volatile("s_waitcnt lgkmcnt(0)" ::: "memory");
    int row = l >> 3, c = l & 7;
    uint4 v0 = *reinterpret_cast<const uint4*>(&lg[w][row][c * 8]);
    uint4 v1 = *reinterpret_cast<const uint4*>(&lg[w][8 + row][c * 8]);
    *reinterpret_cast<uint4*>(gb + (size_t)(n0 + row) * 64 + c * 8) = v0;
    *reinterpret_cast<uint4*>(gb + (size_t)(n0 + 8 + row) * 64 + c * 8) = v1;
  }
}

// ---- GAT layer 2 aggregation + frame mean: GROUP(8 lanes)-PER-NODE ----
__global__ void __launch_bounds__(256)
k_agg2mean(const int* __restrict__ rowptr, const int* __restrict__ csr,
           const unsigned short* __restrict__ gtab, const float* __restrict__ as2,
           const float* __restrict__ ad2, float* __restrict__ emb) {
  __shared__ float part[32][64];
  int t = threadIdx.x;
  int w = t >> 6, l = t & 63;
  int grp = l >> 3, q = l & 7;
  int f = blockIdx.x / BPF;
  int gf = (blockIdx.x - f * BPF) * 32 + w * 8 + grp;   // group id within frame
  const int stride = BPF * 32;
  float m0 = 0.f, m1 = 0.f, m2 = 0.f, m3 = 0.f, m4 = 0.f, m5 = 0.f, m6 = 0.f, m7 = 0.f;
  for (int j = gf; j < NN_F; j += stride) {
    int n = f * NN_F + j;
    float adv = ad2[n];
    float e0 = fexp(lrelu02(as2[n] + adv));
    uint4 pv = *reinterpret_cast<const uint4*>(gtab + (size_t)n * 64 + q * 8);
    float a0 = e0 * bf_lo(pv.x), a1 = e0 * bf_hi(pv.x);
    float a2 = e0 * bf_lo(pv.y), a3 = e0 * bf_hi(pv.y);
    float a4 = e0 * bf_lo(pv.z), a5 = e0 * bf_hi(pv.z);
    float a6 = e0 * bf_lo(pv.w), a7 = e0 * bf_hi(pv.w);
    float den = e0;
    int s0 = rowptr[n], s1 = rowptr[n + 1];
    int i = s0;
    for (; i + 4 <= s1; i += 4) {   // 4-way unroll
      int sa = csr[i], sb = csr[i + 1], sc = csr[i + 2], sd = csr[i + 3];
      float ea = fexp(lrelu02(as2[sa] + adv));
      float eb = fexp(lrelu02(as2[sb] + adv));
      float ec = fexp(lrelu02(as2[sc] + adv));
      float ed = fexp(lrelu02(as2[sd] + adv));
      uint4 va = *reinterpret_cast<const uint4*>(gtab + (size_t)sa * 64 + q * 8);
      uint4 vb = *reinterpret_cast<const uint4*>(gtab + (size_t)sb * 64 + q * 8);
      uint4 vc = *reinterpret_cast<const uint4*>(gtab + (size_t)sc * 64 + q * 8);
      uint4 vd = *reinterpret_cast<const uint4*>(gtab + (size_t)sd * 64 + q * 8);
      a0 = fmaf(ea, bf_lo(va.x), a0); a1 = fmaf(ea, bf_hi(va.x), a1);
      a2 = fmaf(ea, bf_lo(va.y), a2); a3 = fmaf(ea, bf_hi(va.y), a3);
      a4 = fmaf(ea, bf_lo(va.z), a4); a5 = fmaf(ea, bf_hi(va.z), a5);
      a6 = fmaf(ea, bf_lo(va.w), a6); a7 = fmaf(ea, bf_hi(va.w), a7);
      a0 = fmaf(eb, bf_lo(vb.x), a0); a1 = fmaf(eb, bf_hi(vb.x), a1);
      a2 = fmaf(eb, bf_lo(vb.y), a2); a3 = fmaf(eb, bf_hi(vb.y), a3);
      a4 = fmaf(eb, bf_lo(vb.z), a4); a5 = fmaf(eb, bf_hi(vb.z), a5);
      a6 = fmaf(eb, bf_lo(vb.w), a6); a7 = fmaf(eb, bf_hi(vb.w), a7);
      a0 = fmaf(ec, bf_lo(vc.x), a0); a1 = fmaf(ec, bf_hi(vc.x), a1);
      a2 = fmaf(ec, bf_lo(vc.y), a2); a3 = fmaf(ec, bf_hi(vc.y), a3);
      a4 = fmaf(ec, bf_lo(vc.z), a4); a5 = fmaf(ec, bf_hi(vc.z), a5);
      a6 = fmaf(ec, bf_lo(vc.w), a6); a7 = fmaf(ec, bf_hi(vc.w), a7);
      a0 = fmaf(ed, bf_lo(vd.x), a0); a1 = fmaf(ed, bf_hi(vd.x), a1);
      a2 = fmaf(ed, bf_lo(vd.y), a2); a3 = fmaf(ed, bf_hi(vd.y), a3);
      a4 = fmaf(ed, bf_lo(vd.z), a4); a5 = fmaf(ed, bf_hi(vd.z), a5);
      a6 = fmaf(ed, bf_lo(vd.w), a6); a7 = fmaf(ed, bf_hi(vd.w), a7);
      den += (ea + eb) + (ec + ed);
    }
    for (; i < s1; i++) {
      int src = csr[i];
      EDGE_ACC(gtab, src, as2, src)
    }
    float inv = 1.f / den;
    m0 = fmaf(a0, inv, m0); m1 = fmaf(a1, inv, m1);
    m2 = fmaf(a2, inv, m2); m3 = fmaf(a3, inv, m3);
    m4 = fmaf(a4, inv, m4); m5 = fmaf(a5, inv, m5);
    m6 = fmaf(a6, inv, m6); m7 = fmaf(a7, inv, m7);
  }
  float4* pr = reinterpret_cast<float4*>(&part[w * 8 + grp][q * 8]);
  pr[0] = make_float4(m0, m1, m2, m3);
  pr[1] = make_float4(m4, m5, m6, m7);
  __syncthreads();
  if (t < 64) {
    float s = 0.f;
#pragma unroll
    for (int r = 0; r < 32; r++) s += part[r][t];
    atomicAdd(&emb[f * 64 + t], s * (1.0f / NN_F));
  }
}

// ---------------- tiny transformer: 1024 threads, 16-lane-group shuffle GEMVs ----------
__device__ __forceinline__ float grp16_reduce(float p) {
#pragma unroll
  for (int off = 1; off < 16; off <<= 1) p += __shfl_xor(p, off, 64);
  return p;
}

__global__ void __launch_bounds__(1024)
k_transformer(const float* __restrict__ emb, const float* __restrict__ b2,
              const float* __restrict__ Wqkv, const float* __restrict__ bqkv,
              const float* __restrict__ Wo, const float* __restrict__ bo,
              const float* __restrict__ ln1w, const float* __restrict__ ln1b,
              const float* __restrict__ Wff1, const float* __restrict__ bff1,
              const float* __restrict__ Wff2, const float* __restrict__ bff2,
              const float* __restrict__ ln2w, const float* __restrict__ ln2b,
              const float* __restrict__ Wh1, const float* __restrict__ bh1,
              const float* __restrict__ Wh2, const float* __restrict__ bh2,
              float* __restrict__ out) {
  __shared__ float seq[5][64];
  __shared__ float qkv[5][192];
  __shared__ float att[4][5][5];
  __shared__ float aob[5][64];
  __shared__ float ffb[5][128];
  __shared__ float tmp[5][64];
  __shared__ float hid[32];
  int t = threadIdx.x;
  int l = t & 63, w = t >> 6;        // 16 waves
  int g = l >> 4, q = l & 15;        // 4 groups of 16 lanes

  if (t < 320) seq[t >> 6][t & 63] = emb[t] + b2[t & 63];
  __syncthreads();

  for (int ly = 0; ly < 3; ly++) {
    const float* Wq  = Wqkv + ly * 12288; const float* bq  = bqkv + ly * 192;
    const float* Wol = Wo   + ly * 4096;  const float* bol = bo   + ly * 64;
    const float* w1  = ln1w + ly * 64;    const float* bb1 = ln1b + ly * 64;
    const float* Wf1 = Wff1 + ly * 8192;  const float* bf1 = bff1 + ly * 128;
    const float* Wf2 = Wff2 + ly * 8192;  const float* bf2 = bff2 + ly * 64;
    const float* w2  = ln2w + ly * 64;    const float* bb2 = ln2b + ly * 64;

    for (int o = w * 4 + g; o < 960; o += 64) {
      int s = o / 192, j = o - s * 192;
      float4 wv = *reinterpret_cast<const float4*>(&Wq[j * 64 + q * 4]);
      float4 xv = *reinterpret_cast<const float4*>(&seq[s][q * 4]);
      float p = wv.x * xv.x + wv.y * xv.y + wv.z * xv.z + wv.w * xv.w;
      p = grp16_reduce(p);
      if (q == 0) qkv[s][j] = p + bq[j];
    }
    __syncthreads();

    if (t < 100) {
      int hh = t / 25, qs = (t / 5) % 5, ks = t % 5;
      float acc = 0.f;
      for (int d = 0; d < 16; d++)
        acc = fmaf(qkv[qs][hh * 16 + d], qkv[ks][64 + hh * 16 + d], acc);
      att[hh][qs][ks] = acc * 0.25f;
    }
    __syncthreads();
    if (t < 20) {
      int hh = t / 5, qs = t % 5;
      float m = att[hh][qs][0];
      for (int k2 = 1; k2 < 5; k2++) m = fmaxf(m, att[hh][qs][k2]);
      float ss = 0.f;
      for (int k2 = 0; k2 < 5; k2++) { float v = expf(att[hh][qs][k2] - m); att[hh][qs][k2] = v; ss += v; }
      float inv = 1.f / ss;
      for (int k2 = 0; k2 < 5; k2++) att[hh][qs][k2] *= inv;
    }
    __syncthreads();

    if (t < 320) {
      int s = t >> 6, j = t & 63, hh = j >> 4;
      float acc = 0.f;
      for (int k2 = 0; k2 < 5; k2++) acc = fmaf(att[hh][s][k2], qkv[k2][128 + j], acc);
      aob[s][j] = acc;
    }
    __syncthreads();

    for (int o = w * 4 + g; o < 320; o += 64) {
      int s = o >> 6, c = o & 63;
      float4 wv = *reinterpret_cast<const float4*>(&Wol[c * 64 + q * 4]);
      float4 xv = *reinterpret_cast<const float4*>(&aob[s][q * 4]);
      float p = wv.x * xv.x + wv.y * xv.y + wv.z * xv.z + wv.w * xv.w;
      p = grp16_reduce(p);
      if (q == 0) tmp[s][c] = seq[s][c] + p + bol[c];
    }
    __syncthreads();

    if (w < 5) {
      float v = tmp[w][l];
      float s1 = v, s2 = v * v;
#pragma unroll
      for (int off = 1; off < 64; off <<= 1) {
        s1 += __shfl_xor(s1, off, 64);
        s2 += __shfl_xor(s2, off, 64);
      }
      float m = s1 * (1.f / 64.f);
      float var = s2 * (1.f / 64.f) - m * m;
      float inv = 1.f / sqrtf(var + 1e-5f);
      seq[w][l] = (v - m) * inv * w1[l] + bb1[l];
    }
    __syncthreads();

    for (int o = w * 4 + g; o < 640; o += 64) {
      int s = o >> 7, j = o & 127;
      float4 wv = *reinterpret_cast<const float4*>(&Wf1[j * 64 + q * 4]);
      float4 xv = *reinterpret_cast<const float4*>(&seq[s][q * 4]);
      float p = wv.x * xv.x + wv.y * xv.y + wv.z * xv.z + wv.w * xv.w;
      p = grp16_reduce(p);
      if (q == 0) ffb[s][j] = fmaxf(p + bf1[j], 0.f);
    }
    __syncthreads();

    for (int o = w * 4 + g; o < 320; o += 64) {
      int s = o >> 6, c = o & 63;
      float4 wa = *reinterpret_cast<const float4*>(&Wf2[c * 128 + q * 8]);
      float4 wb = *reinterpret_cast<const float4*>(&Wf2[c * 128 + q * 8 + 4]);
      float4 xa = *reinterpret_cast<const float4*>(&ffb[s][q * 8]);
      float4 xb = *reinterpret_cast<const float4*>(&ffb[s][q * 8 + 4]);
      float p = wa.x * xa.x + wa.y * xa.y + wa.z * xa.z + wa.w * xa.w
              + wb.x * xb.x + wb.y * xb.y + wb.z * xb.z + wb.w * xb.w;
      p = grp16_reduce(p);
      if (q == 0) tmp[s][c] = seq[s][c] + p + bf2[c];
    }
    __syncthreads();

    if (w < 5) {
      float v = tmp[w][l];
      float s1 = v, s2 = v * v;
#pragma unroll
      for (int off = 1; off < 64; off <<= 1) {
        s1 += __shfl_xor(s1, off, 64);
        s2 += __shfl_xor(s2, off, 64);
      }
      float m = s1 * (1.f / 64.f);
      float var = s2 * (1.f / 64.f) - m * m;
      float inv = 1.f / sqrtf(var + 1e-5f);
      seq[w][l] = (v - m) * inv * w2[l] + bb2[l];
    }
    __syncthreads();
  }

  for (int o = w * 4 + g; o < 32; o += 64) {
    float4 wv = *reinterpret_cast<const float4*>(&Wh1[o * 64 + q * 4]);
    float4 xv = *reinterpret_cast<const float4*>(&seq[4][q * 4]);
    float p = wv.x * xv.x + wv.y * xv.y + wv.z * xv.z + wv.w * xv.w;
    p = grp16_reduce(p);
    if (q == 0) hid[o] = fmaxf(p + bh1[o], 0.f);
  }
  __syncthreads();
  if (t < 2) {
    float acc = bh2[t];
    for (int j = 0; j < 32; j++) acc = fmaf(hid[j], Wh2[t * 32 + j], acc);
    out[t] = acc;
  }
}

extern "C" void kernel_launch(void* const* d_in, const int* in_sizes, int n_in,
                              void* d_out, int out_size, void* d_ws, size_t ws_size,
                              hipStream_t stream) {
  const float* x     = (const float*)d_in[0];
  const int*   ei    = (const int*)d_in[1];
  const float* W1    = (const float*)d_in[2];
  const float* attS1 = (const float*)d_in[3];
  const float* attD1 = (const float*)d_in[4];
  const float* b1    = (const float*)d_in[5];
  const float* W2    = (const float*)d_in[6];
  const float* attS2 = (const float*)d_in[7];
  const float* attD2 = (const float*)d_in[8];
  const float* b2    = (const float*)d_in[9];
  const float* tWqkv = (const float*)d_in[10];
  const float* tbqkv = (const float*)d_in[11];
  const float* tWo   = (const float*)d_in[12];
  const float* tbo   = (const float*)d_in[13];
  const float* tln1w = (const float*)d_in[14];
  const float* tln1b = (const float*)d_in[15];
  const float* tWff1 = (const float*)d_in[16];
  const float* tbff1 = (const float*)d_in[17];
  const float* tWff2 = (const float*)d_in[18];
  const float* tbff2 = (const float*)d_in[19];
  const float* tln2w = (const float*)d_in[20];
  const float* tln2b = (const float*)d_in[21];
  const float* Wh1   = (const float*)d_in[22];
  const float* bh1   = (const float*)d_in[23];
  const float* Wh2   = (const float*)d_in[24];
  const float* bh2   = (const float*)d_in[25];
  float* out = (float*)d_out;

  auto need_bytes = [](int F) -> size_t {
    size_t NT = (size_t)F * NN_F, ET = (size_t)F * NE_F;
    return (NT * 18 + 320) * 4 + (NT * 192 + ET) * 2 + (NT * 2 + 1 + 2048 + ET) * 4;
  };
  const int F = (ws_size >= need_bytes(5)) ? 5 : 1;
  const int NT = F * NN_F, ET = F * NE_F;

  float* ws  = (float*)d_ws;
  float* as1 = ws;                          // NT*8
  float* ad1 = as1 + (size_t)NT * 8;        // NT*8
  float* as2 = ad1 + (size_t)NT * 8;        // NT
  float* ad2 = as2 + NT;                    // NT
  float* emb = ad2 + NT;                    // 320
  unsigned short* h1b   = (unsigned short*)(emb + 320);   // NT*64 bf16
  unsigned short* gb    = h1b + (size_t)NT * 64;          // NT*64 bf16
  unsigned short* out1b = gb + (size_t)NT * 64;           // NT*64 bf16
  int* deg    = (int*)(out1b + (size_t)NT * 64);          // NT
  int* rowptr = deg + NT;                   // NT+1
  int* bsum   = rowptr + NT + 1;            // <=1024
  int* boff   = bsum + 1024;                // <=1024
  unsigned short* rank = (unsigned short*)(boff + 1024);  // ET (ushort)
  int* csr    = (int*)(rank + ET);          // ET

  (void)hipMemsetAsync(emb, 0, 320 * sizeof(float), stream);

  const int nblk = (NT + 255) / 256;
  const int edge4Blocks = ((ET >> 2) + 255) / 256;
  const int agg1Blocks = (NT / 8 + 3) / 4;  // group(8 lanes) per node, 32 groups/block
  const int node1Blocks = 2048;
  const int node2Blocks = 1024;             // wave = 16-node MFMA tile

  for (int f0 = 0; f0 < 5; f0 += F) {
    const float* xf = x + (size_t)f0 * NN_F * 13;
    const int* eif  = ei + (size_t)f0 * 2 * NE_F;

    (void)hipMemsetAsync(deg, 0, NT * sizeof(int), stream);
    // fused: CSR rank pass (atomic-bound) runs concurrently with node1 (LDS/VALU-bound)
    k_rank_node1<<<edge4Blocks + node1Blocks, 256, 0, stream>>>(
        eif, deg, rank, F, edge4Blocks,
        xf, W1, attS1, attD1, h1b, as1, ad1, NT, node1Blocks);
    k_scan1<<<nblk, 256, 0, stream>>>(deg, bsum, NT);
    k_scan2<<<1, 1024, 0, stream>>>(bsum, boff, nblk);
    k_scan3<<<nblk, 256, 0, stream>>>(deg, boff, rowptr, NT, ET);
    k_place<<<edge4Blocks, 256, 0, stream>>>(eif, rowptr, rank, csr, F);

    k_agg1<<<agg1Blocks, 256, 0, stream>>>(rowptr, csr, h1b, as1, ad1, out1b, NT);
    k_node2<<<node2Blocks, 256, 0, stream>>>(out1b, b1, W2, attS2, attD2, gb, as2, ad2, NT);
    k_agg2mean<<<F * BPF, 256, 0, stream>>>(rowptr, csr, gb, as2, ad2, emb + f0 * 64);
  }

  k_transformer<<<1, 1024, 0, stream>>>(emb, b2, tWqkv, tbqkv, tWo, tbo, tln1w, tln1b,
                                        tWff1, tbff1, tWff2, tbff2, tln2w, tln2b,
                                        Wh1, bh1, Wh2, bh2, out);
}